// Round 8
// baseline (478.529 us; speedup 1.0000x reference)
//
#include <hip/hip_runtime.h>

namespace {

typedef float v2f __attribute__((ext_vector_type(2)));

constexpr int NTAGS = 64;
constexpr int START_T = 62;
constexpr int STOP_T = 63;
constexpr int Bc = 512;
constexpr int Lc = 512;
constexpr int NCH = 4;  // batches (independent scan chains) per wave

template <int CTRL>
__device__ __forceinline__ float dpp_add(float x) {
  // x + quad_perm(x): pure-VALU cross-lane add within groups of 4 lanes.
  return x + __int_as_float(__builtin_amdgcn_update_dpp(
                 0, __float_as_int(x), CTRL, 0xf, 0xf, true));
}

__device__ __forceinline__ float wave_max(float v) {
#pragma unroll
  for (int off = 32; off >= 1; off >>= 1)
    v = fmaxf(v, __shfl_xor(v, off, 64));
  return v;
}

__device__ __forceinline__ float wave_sum(float v) {
#pragma unroll
  for (int off = 32; off >= 1; off >>= 1)
    v += __shfl_xor(v, off, 64);
  return v;
}

// ---------------------------------------------------------------------------
// Forward scan: 4 independent batch-chains per wave, round-robin interleaved
// so each chain's LDS write->read latency hides under the other 3 chains'
// issue. Per chain-step (R4-verified math, absmax 0.0):
//   lane -> (lr = lane>>2, c = lane&3); lane owns rows {lr+16k} and j-chunk c.
//   v stored in LDS in sigma-order sigma(j) = (j&15)*4 + (j>>4) so each
//   chunk is 4 contiguous float4 and the store address is word==lane.
//   Exp-domain state: v = exp(alpha - Msum*ln2); power-of-2 rescale from the
//   stale exponent of word 0 (exact integer Msum bookkeeping).
// ---------------------------------------------------------------------------
__global__ __launch_bounds__(64, 1) void crf_scan(
    const float* __restrict__ inputs,   // [B, L, 64]
    const int* __restrict__ mask,       // [B, L]
    const float* __restrict__ trans,    // [64, 64]
    float* __restrict__ den) {          // [B] log-denominator
  __shared__ float4 vb4[NCH][16];

  const int lane = threadIdx.x;
  const int lr = lane >> 2;
  const int c = lane & 3;
  const int bbase = blockIdx.x * NCH;

  // ---- E = exp(trans) fragments, shared by all chains ----
#define DECLE(k) v2f E##k##_0, E##k##_1, E##k##_2, E##k##_3, \
                     E##k##_4, E##k##_5, E##k##_6, E##k##_7;
  DECLE(0) DECLE(1) DECLE(2) DECLE(3)
#define LOADE(k)                                                       \
  {                                                                    \
    const float* tp = trans + (lr + 16 * k) * NTAGS + 4 * c;           \
    E##k##_0 = (v2f){__expf(tp[0]),  __expf(tp[16])};                  \
    E##k##_1 = (v2f){__expf(tp[32]), __expf(tp[48])};                  \
    E##k##_2 = (v2f){__expf(tp[1]),  __expf(tp[17])};                  \
    E##k##_3 = (v2f){__expf(tp[33]), __expf(tp[49])};                  \
    E##k##_4 = (v2f){__expf(tp[2]),  __expf(tp[18])};                  \
    E##k##_5 = (v2f){__expf(tp[34]), __expf(tp[50])};                  \
    E##k##_6 = (v2f){__expf(tp[3]),  __expf(tp[19])};                  \
    E##k##_7 = (v2f){__expf(tp[35]), __expf(tp[51])};                  \
  }
  LOADE(0) LOADE(1) LOADE(2) LOADE(3)

  // ---- per-chain state (named, no runtime-indexed arrays) ----
#define DECLC(i)                                                       \
  float4 u0_##i, u1_##i, u2_##i, u3_##i;                               \
  float wA_##i[4][4], wB_##i[4][4];                                    \
  int Ms_##i = 0, mr_##i, mrn_##i;                                     \
  const float* pe_##i = inputs + (size_t)(bbase + i) * Lc * NTAGS + lr;\
  const int* mp_##i = mask + (size_t)(bbase + i) * Lc;
  DECLC(0) DECLC(1) DECLC(2) DECLC(3)

  // init v = onehot(START_T=62); sigma(62) = 59
#pragma unroll
  for (int i = 0; i < NCH; ++i)
    ((float*)&vb4[i][0])[lane] = (lane == 59) ? 1.0f : 0.0f;
  __builtin_amdgcn_wave_barrier();

#define ULOAD(i)                                                       \
  {                                                                    \
    u0_##i = vb4[i][4 * c + 0];                                        \
    u1_##i = vb4[i][4 * c + 1];                                        \
    u2_##i = vb4[i][4 * c + 2];                                        \
    u3_##i = vb4[i][4 * c + 3];                                        \
  }
  ULOAD(0) ULOAD(1) ULOAD(2) ULOAD(3)

#define ROWF(k, i)                                                     \
    v2f a##k##0 = E##k##_0 * (v2f){u0_##i.x, u0_##i.y};                \
    v2f a##k##1 = E##k##_1 * (v2f){u0_##i.z, u0_##i.w};                \
    a##k##0 += E##k##_2 * (v2f){u1_##i.x, u1_##i.y};                   \
    a##k##1 += E##k##_3 * (v2f){u1_##i.z, u1_##i.w};                   \
    a##k##0 += E##k##_4 * (v2f){u2_##i.x, u2_##i.y};                   \
    a##k##1 += E##k##_5 * (v2f){u2_##i.z, u2_##i.w};                   \
    a##k##0 += E##k##_6 * (v2f){u3_##i.x, u3_##i.y};                   \
    a##k##1 += E##k##_7 * (v2f){u3_##i.z, u3_##i.w};

#define STEP(i, W0, W1, W2, W3, MIDX)                                  \
  {                                                                    \
    const int sb =                                                     \
        __builtin_amdgcn_readfirstlane(__float_as_int(u0_##i.x));      \
    const unsigned e0 = ((unsigned)sb >> 23) & 0xffu;                  \
    const int d = (e0 == 0u) ? 0 : (int)e0 - 127;                      \
    Ms_##i += d;                                                       \
    const float rs = __uint_as_float((unsigned)(127 - d) << 23);       \
    const int mv = __builtin_amdgcn_readlane(mr_##i, (MIDX));          \
    float s0, s1, s2, s3;                                              \
    if (__builtin_expect(mv, 1)) {                                     \
      ROWF(0, i) ROWF(1, i) ROWF(2, i) ROWF(3, i)                      \
      v2f t0 = a00 + a01, t1 = a10 + a11;                              \
      v2f t2 = a20 + a21, t3 = a30 + a31;                              \
      float r0 = t0.x + t0.y, r1 = t1.x + t1.y;                        \
      float r2 = t2.x + t2.y, r3 = t3.x + t3.y;                        \
      r0 = dpp_add<0xB1>(r0); r1 = dpp_add<0xB1>(r1);                  \
      r2 = dpp_add<0xB1>(r2); r3 = dpp_add<0xB1>(r3);                  \
      r0 = dpp_add<0x4E>(r0); r1 = dpp_add<0x4E>(r1);                  \
      r2 = dpp_add<0x4E>(r2); r3 = dpp_add<0x4E>(r3);                  \
      s0 = r0 * ((W0) * rs); s1 = r1 * ((W1) * rs);                    \
      s2 = r2 * ((W2) * rs); s3 = r3 * ((W3) * rs);                    \
    } else {                                                           \
      v2f q0 = ((v2f){u0_##i.x, u0_##i.y} + (v2f){u0_##i.z, u0_##i.w}) + \
               ((v2f){u1_##i.x, u1_##i.y} + (v2f){u1_##i.z, u1_##i.w}); \
      v2f q1 = ((v2f){u2_##i.x, u2_##i.y} + (v2f){u2_##i.z, u2_##i.w}) + \
               ((v2f){u3_##i.x, u3_##i.y} + (v2f){u3_##i.z, u3_##i.w}); \
      v2f qq = q0 + q1;                                                \
      float ss = qq.x + qq.y;                                          \
      ss = dpp_add<0xB1>(ss); ss = dpp_add<0x4E>(ss);                  \
      ss *= rs;                                                        \
      s0 = s1 = s2 = s3 = ss;                                          \
    }                                                                  \
    /* lane writes v'[lr+16c]: sigma(lr+16c) == lane. select s_c */    \
    const float slo = (c & 1) ? s1 : s0;                               \
    const float shi = (c & 1) ? s3 : s2;                               \
    const float sw = (c & 2) ? shi : slo;                              \
    __builtin_amdgcn_wave_barrier();                                   \
    ((float*)&vb4[i][0])[lane] = sw;                                   \
    __builtin_amdgcn_wave_barrier();                                   \
    ULOAD(i)                                                           \
  }

  // w = exp(emit) prefetch: per chain, two banks of 4 steps x 4 rows.
#define PRE(W, i, ST)                                                  \
  {                                                                    \
    int s_ = (ST); s_ = s_ > (Lc - 4) ? (Lc - 4) : s_;                 \
    _Pragma("unroll") for (int q_ = 0; q_ < 4; ++q_) {                 \
      const float* pp = pe_##i + (size_t)(s_ + q_) * NTAGS;            \
      W[q_][0] = __expf(pp[0]);                                        \
      W[q_][1] = __expf(pp[16]);                                       \
      W[q_][2] = __expf(pp[32]);                                       \
      W[q_][3] = __expf(pp[48]);                                       \
    }                                                                  \
  }

  PRE(wA_0, 0, 0) PRE(wA_1, 1, 0) PRE(wA_2, 2, 0) PRE(wA_3, 3, 0)
  mr_0 = mp_0[lane]; mr_1 = mp_1[lane];
  mr_2 = mp_2[lane]; mr_3 = mp_3[lane];

#define S4(BANK, S, MIDX)                                              \
  STEP(0, BANK##_0[S][0], BANK##_0[S][1], BANK##_0[S][2],              \
       BANK##_0[S][3], MIDX)                                           \
  STEP(1, BANK##_1[S][0], BANK##_1[S][1], BANK##_1[S][2],              \
       BANK##_1[S][3], MIDX)                                           \
  STEP(2, BANK##_2[S][0], BANK##_2[S][1], BANK##_2[S][2],              \
       BANK##_2[S][3], MIDX)                                           \
  STEP(3, BANK##_3[S][0], BANK##_3[S][1], BANK##_3[S][2],              \
       BANK##_3[S][3], MIDX)

  for (int chunk = 0; chunk < 8; ++chunk) {
    const int cbase = chunk * 64;
    const int nb = (chunk < 7 ? cbase + 64 : cbase) + lane;
    mrn_0 = mp_0[nb]; mrn_1 = mp_1[nb];
    mrn_2 = mp_2[nb]; mrn_3 = mp_3[nb];
    for (int gp = 0; gp < 8; ++gp) {
      const int base = cbase + gp * 8;
      const int mb = gp * 8;
      PRE(wB_0, 0, base + 4) PRE(wB_1, 1, base + 4)
      PRE(wB_2, 2, base + 4) PRE(wB_3, 3, base + 4)
      S4(wA, 0, mb + 0)
      S4(wA, 1, mb + 1)
      S4(wA, 2, mb + 2)
      S4(wA, 3, mb + 3)
      PRE(wA_0, 0, base + 8) PRE(wA_1, 1, base + 8)
      PRE(wA_2, 2, base + 8) PRE(wA_3, 3, base + 8)
      S4(wB, 0, mb + 4)
      S4(wB, 1, mb + 5)
      S4(wB, 2, mb + 6)
      S4(wB, 3, mb + 7)
    }
    mr_0 = mrn_0; mr_1 = mrn_1; mr_2 = mrn_2; mr_3 = mrn_3;
  }

  // ---- epilogue: logden = logsumexp(alpha + trans[STOP,:]) per chain ----
  const int sig = ((lane & 15) << 2) | (lane >> 4);  // sigma(lane)
  const float* tstop = trans + STOP_T * NTAGS;
#define EPI(i)                                                         \
  {                                                                    \
    const float mf_ = (float)Ms_##i;                                   \
    const float C_ = fmaf(mf_, -2.1219444e-4f, mf_ * 0.693359375f);    \
    float alphav = __logf(((const float*)&vb4[i][0])[sig]) + C_;       \
    float term = alphav + tstop[lane];                                 \
    float mx = wave_max(term);                                         \
    float sden = wave_sum(__expf(term - mx));                          \
    if (lane == 0) den[bbase + i] = mx + __logf(sden);                 \
  }
  EPI(0) EPI(1) EPI(2) EPI(3)
}

// ---------------------------------------------------------------------------
// Numerator score (exact, fully parallel): one wave per batch. (R7-verified)
// ---------------------------------------------------------------------------
__global__ void crf_num(const float* __restrict__ inputs,
                        const int* __restrict__ tags,
                        const int* __restrict__ mask,
                        const float* __restrict__ trans,
                        float* __restrict__ num) {
  const int b = blockIdx.x;
  const int lane = threadIdx.x;
  const float* emit_base = inputs + (size_t)b * Lc * NTAGS;
  const int* tags_b = tags + b * Lc;
  const int* mask_b = mask + b * Lc;

  float sc = 0.0f;
  for (int l = lane; l < Lc; l += 64) {
    int tl = tags_b[l];
    float mfl = (float)mask_b[l];
    if (l < Lc - 1) {
      int tn = tags_b[l + 1];
      float mfn = (float)mask_b[l + 1];
      sc += trans[tn * NTAGS + tl] * mfn +
            emit_base[(size_t)l * NTAGS + tl] * mfl;
    } else {
      sc += trans[STOP_T * NTAGS + tl] +
            emit_base[(size_t)l * NTAGS + tl] * mfl;
    }
  }
  if (lane == 0) sc += trans[tags_b[0] * NTAGS + START_T];
  float score = wave_sum(sc);
  if (lane == 0) num[b] = score;
}

__global__ void crf_reduce(const float* __restrict__ num,
                           const float* __restrict__ den,
                           float* __restrict__ out) {
  const int lane = threadIdx.x;
  float s = 0.0f;
  for (int i = lane; i < Bc; i += 64) s += num[i] - den[i];
  s = wave_sum(s);
  if (lane == 0) out[0] = s;
}

}  // namespace

extern "C" void kernel_launch(void* const* d_in, const int* in_sizes, int n_in,
                              void* d_out, int out_size, void* d_ws,
                              size_t ws_size, hipStream_t stream) {
  const float* inputs = (const float*)d_in[0];
  const int* tags = (const int*)d_in[1];
  const int* mask = (const int*)d_in[2];
  const float* trans = (const float*)d_in[3];
  float* out = (float*)d_out;
  float* num = (float*)d_ws;   // [512]
  float* den = num + Bc;       // [512]

  crf_scan<<<Bc / NCH, 64, 0, stream>>>(inputs, mask, trans, den);
  crf_num<<<Bc, 64, 0, stream>>>(inputs, tags, mask, trans, num);
  crf_reduce<<<1, 64, 0, stream>>>(num, den, out);
}

// Round 9
// 170.596 us; speedup vs baseline: 2.8050x; 2.8050x over previous
//
#include <hip/hip_runtime.h>

namespace {

typedef float v2f __attribute__((ext_vector_type(2)));

constexpr int NTAGS = 64;
constexpr int START_T = 62;
constexpr int STOP_T = 63;
constexpr int Bc = 512;
constexpr int Lc = 512;
constexpr int HL = 256;  // half length

__device__ __forceinline__ float wave_sum(float v) {
#pragma unroll
  for (int off = 32; off >= 1; off >>= 1)
    v += __shfl_xor(v, off, 64);
  return v;
}

// ---------------------------------------------------------------------------
// Bidirectional split scan. One block (128 thr = 2 waves) per batch.
//   Z = r^T (M_511 ... M_0) e_START,  M_l = diag(w_l) E,  w_l = exp(emit_l),
//   E = exp(trans)  (mask_l==0 => M_l = ones-matrix, no w).
// Wave 0 (fwd):  v_{k+1} = M_k v_k, k = 0..255          (w applied after matvec)
// Wave 1 (bwd):  y_l = E^T z_l;  z_{l-1} = w'_{l-1} ∘ y_l,  l = 511..256,
//                z_511 = gate(mask_511) w_511 ∘ r,  r = exp(trans[STOP,:]).
// Join: logZ = log(v_256 · y_256) + (MsF + MsB) ln2.
// Exp-domain state with per-step power-of-2 rescale (exact integer Msum) —
// the R3-verified step body (absmax 0.0), only the else-branch W differs.
// ---------------------------------------------------------------------------
__global__ __launch_bounds__(128, 1) void crf_scan(
    const float* __restrict__ inputs,   // [B, L, 64]
    const int* __restrict__ tags,       // [B, L]
    const int* __restrict__ mask,       // [B, L]
    const float* __restrict__ trans,    // [64, 64]
    float* __restrict__ partial) {      // [B]
  __shared__ float4 vb4s[2][16];
  __shared__ int shMs[2];
  __shared__ float shNum[2];

  const int tid = threadIdx.x;
  const int lane = tid & 63;
  const int wid = tid >> 6;
  const bool bwd = (wid != 0);
  const int b = blockIdx.x;

  float* vb1 = reinterpret_cast<float*>(&vb4s[wid][0]);
  const float4* vb4 = &vb4s[wid][0];

#define FOR16(X) X(0) X(1) X(2) X(3) X(4) X(5) X(6) X(7) \
                 X(8) X(9) X(10) X(11) X(12) X(13) X(14) X(15)

  // E fragments: fwd lane i holds row exp(trans[i][:]);
  //              bwd lane j holds column exp(trans[:][j]) (= E^T row).
  const float* tbase = trans + (bwd ? lane : lane * NTAGS);
  const int js = bwd ? NTAGS : 1;
#define DECL_E(q) v2f Ea##q, Eb##q;
  FOR16(DECL_E)
#define LOAD_E(q)                                                      \
  {                                                                    \
    Ea##q = (v2f){__expf(tbase[(4 * q + 0) * js]),                     \
                  __expf(tbase[(4 * q + 1) * js])};                    \
    Eb##q = (v2f){__expf(tbase[(4 * q + 2) * js]),                     \
                  __expf(tbase[(4 * q + 3) * js])};                    \
  }
  FOR16(LOAD_E)

  const float* emit_base = inputs + (size_t)b * Lc * NTAGS;
  const float* pe = emit_base + lane;
  const int* mask_b = mask + b * Lc;
  const int* tags_b = tags + b * Lc;

  int Msum = 0;
  if (!bwd) {
    vb1[lane] = (lane == START_T) ? 1.0f : 0.0f;
  } else {
    const float rr = __expf(trans[STOP_T * NTAGS + lane]);
    const float wl = (mask_b[Lc - 1] != 0)
                         ? __expf(pe[(size_t)(Lc - 1) * NTAGS])
                         : 1.0f;
    vb1[lane] = rr * wl;  // z_511
  }
  __builtin_amdgcn_wave_barrier();

  // W for step k: fwd -> exp(emit[k]); bwd -> gated exp(emit[510-k]) or 1.
  auto wval = [&](int k) -> float {
    if (!bwd) {
      const int kk = (k < HL) ? k : (HL - 1);
      return __expf(pe[(size_t)kk * NTAGS]);
    } else {
      if (k >= HL - 1) return 1.0f;  // k == 255 (+ prefetch overshoot)
      const int e = (Lc - 2) - k;    // 510 - k
      return (mask_b[e] != 0) ? __expf(pe[(size_t)e * NTAGS]) : 1.0f;
    }
  };
#define PRE(B0, B1, B2, B3, ST)                                        \
  {                                                                    \
    B0 = wval((ST));                                                   \
    B1 = wval((ST) + 1);                                               \
    B2 = wval((ST) + 2);                                               \
    B3 = wval((ST) + 3);                                               \
  }

#define MF(q, A, Bq)                                   \
  {                                                    \
    float4 uu = vb4[q];                                \
    A += Ea##q * (v2f){uu.x, uu.y};                    \
    Bq += Eb##q * (v2f){uu.z, uu.w};                   \
  }
#define MS(q)                                          \
  {                                                    \
    float4 uu = vb4[q];                                \
    a0 += (v2f){uu.x, uu.y};                           \
    a1 += (v2f){uu.z, uu.w};                           \
  }

#define STEP(W, MIDX)                                                  \
  {                                                                    \
    const int mv = __builtin_amdgcn_readlane(mrow, (MIDX));            \
    float s;                                                           \
    if (mv) {                                                          \
      v2f a0 = {0.f, 0.f}, a1 = {0.f, 0.f};                            \
      v2f a2 = {0.f, 0.f}, a3 = {0.f, 0.f};                            \
      MF(0, a0, a1) MF(1, a2, a3) MF(2, a0, a1) MF(3, a2, a3)          \
      MF(4, a0, a1) MF(5, a2, a3) MF(6, a0, a1) MF(7, a2, a3)          \
      MF(8, a0, a1) MF(9, a2, a3) MF(10, a0, a1) MF(11, a2, a3)        \
      MF(12, a0, a1) MF(13, a2, a3) MF(14, a0, a1) MF(15, a2, a3)      \
      v2f t = (a0 + a1) + (a2 + a3);                                   \
      s = (t.x + t.y) * (W);                                           \
    } else {                                                           \
      v2f a0 = {0.f, 0.f}, a1 = {0.f, 0.f};                            \
      MS(0) MS(1) MS(2) MS(3) MS(4) MS(5) MS(6) MS(7)                  \
      MS(8) MS(9) MS(10) MS(11) MS(12) MS(13) MS(14) MS(15)            \
      v2f t = a0 + a1;                                                 \
      s = (t.x + t.y) * (bwd ? (W) : 1.0f);                            \
    }                                                                  \
    const unsigned sb =                                                \
        (unsigned)__builtin_amdgcn_readfirstlane(__float_as_int(s));   \
    const unsigned e0 = (sb >> 23) & 0xffu;                            \
    const int d = (e0 == 0u) ? 0 : (int)e0 - 127;                      \
    Msum += d;                                                         \
    const float rs = __uint_as_float((unsigned)(127 - d) << 23);       \
    const float vv = s * rs;                                           \
    __builtin_amdgcn_wave_barrier();                                   \
    vb1[lane] = vv;                                                    \
    __builtin_amdgcn_wave_barrier();                                   \
  }

  float eA0, eA1, eA2, eA3, eB0, eB1, eB2, eB3;
  PRE(eA0, eA1, eA2, eA3, 0)
  int mrow = mask_b[bwd ? (Lc - 1 - lane) : lane];

  for (int cc = 0; cc < 4; ++cc) {
    const int nc = (cc < 3) ? cc + 1 : cc;
    const int mrow_nxt =
        mask_b[bwd ? (Lc - 1 - nc * 64 - lane) : (nc * 64 + lane)];
    for (int gp = 0; gp < 8; ++gp) {
      const int base = cc * 64 + gp * 8;
      const int mb = gp * 8;
      PRE(eB0, eB1, eB2, eB3, base + 4)
      STEP(eA0, mb + 0) STEP(eA1, mb + 1) STEP(eA2, mb + 2) STEP(eA3, mb + 3)
      PRE(eA0, eA1, eA2, eA3, base + 8)
      STEP(eB0, mb + 4) STEP(eB1, mb + 5) STEP(eB2, mb + 6) STEP(eB3, mb + 7)
    }
    mrow = mrow_nxt;
  }

  // ---- numerator partial: this wave covers l in [wid*256, wid*256+256) ----
  float sc = 0.0f;
#pragma unroll
  for (int t4 = 0; t4 < 4; ++t4) {
    const int l = wid * HL + t4 * 64 + lane;
    const int tl = tags_b[l];
    const float mfl = (float)mask_b[l];
    if (l < Lc - 1) {
      const int tn = tags_b[l + 1];
      const float mfn = (float)mask_b[l + 1];
      sc += trans[tn * NTAGS + tl] * mfn +
            emit_base[(size_t)l * NTAGS + tl] * mfl;
    } else {
      sc += trans[STOP_T * NTAGS + tl] +
            emit_base[(size_t)l * NTAGS + tl] * mfl;
    }
  }
  if (!bwd && lane == 0) sc += trans[tags_b[0] * NTAGS + START_T];
  const float score = wave_sum(sc);
  if (lane == 0) {
    shNum[wid] = score;
    shMs[wid] = Msum;
  }
  __syncthreads();

  // ---- join: logZ = log(v · y) + (MsF + MsB) ln2 ----
  if (wid == 0) {
    const float prod = reinterpret_cast<const float*>(&vb4s[0][0])[lane] *
                       reinterpret_cast<const float*>(&vb4s[1][0])[lane];
    const float sden = wave_sum(prod);
    if (lane == 0) {
      const float mf = (float)(shMs[0] + shMs[1]);
      const float C = fmaf(mf, -2.1219444e-4f, mf * 0.693359375f);
      partial[b] = (shNum[0] + shNum[1]) - (__logf(sden) + C);
    }
  }
}

__global__ void crf_reduce(const float* __restrict__ partial,
                           float* __restrict__ out) {
  const int lane = threadIdx.x;
  float s = 0.0f;
  for (int i = lane; i < Bc; i += 64) s += partial[i];
  s = wave_sum(s);
  if (lane == 0) out[0] = s;
}

}  // namespace

extern "C" void kernel_launch(void* const* d_in, const int* in_sizes, int n_in,
                              void* d_out, int out_size, void* d_ws,
                              size_t ws_size, hipStream_t stream) {
  const float* inputs = (const float*)d_in[0];
  const int* tags = (const int*)d_in[1];
  const int* mask = (const int*)d_in[2];
  const float* trans = (const float*)d_in[3];
  float* out = (float*)d_out;
  float* partial = (float*)d_ws;  // B floats of scratch

  crf_scan<<<Bc, 128, 0, stream>>>(inputs, tags, mask, trans, partial);
  crf_reduce<<<1, 64, 0, stream>>>(partial, out);
}

// Round 10
// 164.047 us; speedup vs baseline: 2.9170x; 1.0399x over previous
//
#include <hip/hip_runtime.h>

namespace {

typedef float v2f __attribute__((ext_vector_type(2)));

constexpr int NTAGS = 64;
constexpr int START_T = 62;
constexpr int STOP_T = 63;
constexpr int Bc = 512;
constexpr int Lc = 512;
constexpr int HL = 256;  // half length

template <int CTRL>
__device__ __forceinline__ float dpp_add(float x) {
  return x + __int_as_float(__builtin_amdgcn_update_dpp(
                 0, __float_as_int(x), CTRL, 0xf, 0xf, true));
}

__device__ __forceinline__ float wave_sum(float v) {
#pragma unroll
  for (int off = 32; off >= 1; off >>= 1)
    v += __shfl_xor(v, off, 64);
  return v;
}

// ---------------------------------------------------------------------------
// Bidirectional split scan, split-dot step body. 1024 one-wave blocks:
// block bid < 512: forward chain of batch bid;  bid >= 512: backward chain.
//   Z = r^T (M_511..M_0) e_START,  M_l = diag(w_l) E (mask=1) or 11^T (mask=0)
//   fwd state f: f' = w_l ∘ (E f);  bwd state S: S' = w'_(e) ∘ (E^T S),
//   init S = w'_511 ∘ r; after 256 steps S = z_256, Z = z_256 · f_256.
// Split-dot (R4-verified): lane -> (lr = lane>>2, c = lane&3); lane owns
// rows {lr+16k} and j-chunk c; v in LDS sigma-order sigma(j)=(j&15)*4+(j>>4);
// per step 4 ds_read_b128 + dpp quad-reduce + uniform ds_write_b32 at
// word==lane (writes row lr+16c, select s_c). Exp-domain rescale: d from
// register-carried rep (lane0's previous write), exact integer Msum.
// ---------------------------------------------------------------------------
__global__ __launch_bounds__(64, 1) void crf_scan(
    const float* __restrict__ inputs,   // [B, L, 64]
    const int* __restrict__ mask,       // [B, L]
    const float* __restrict__ trans,    // [64, 64]
    float* __restrict__ hv,             // [1024, 64] final half-states
    int* __restrict__ msum_out) {       // [1024]
  __shared__ float4 vb4[16];
  float* vb1 = reinterpret_cast<float*>(vb4);

  const int lane = threadIdx.x;
  const int lr = lane >> 2;
  const int c = lane & 3;
  const int bid = blockIdx.x;
  const bool bwd = bid >= Bc;
  const int b = bwd ? bid - Bc : bid;

  // E fragment element: fwd row-major, bwd transposed (prologue-only).
#define TE(ROW, COL) \
  __expf(trans[bwd ? (COL) * NTAGS + (ROW) : (ROW) * NTAGS + (COL)])

#define DECLE(k) v2f E##k##_0, E##k##_1, E##k##_2, E##k##_3, \
                     E##k##_4, E##k##_5, E##k##_6, E##k##_7;
  DECLE(0) DECLE(1) DECLE(2) DECLE(3)
#define LOADE(k)                                                       \
  {                                                                    \
    const int row = lr + 16 * k;                                       \
    const int c4 = 4 * c;                                              \
    E##k##_0 = (v2f){TE(row, c4 + 0), TE(row, c4 + 16)};               \
    E##k##_1 = (v2f){TE(row, c4 + 32), TE(row, c4 + 48)};              \
    E##k##_2 = (v2f){TE(row, c4 + 1), TE(row, c4 + 17)};               \
    E##k##_3 = (v2f){TE(row, c4 + 33), TE(row, c4 + 49)};              \
    E##k##_4 = (v2f){TE(row, c4 + 2), TE(row, c4 + 18)};               \
    E##k##_5 = (v2f){TE(row, c4 + 34), TE(row, c4 + 50)};              \
    E##k##_6 = (v2f){TE(row, c4 + 3), TE(row, c4 + 19)};               \
    E##k##_7 = (v2f){TE(row, c4 + 35), TE(row, c4 + 51)};              \
  }
  LOADE(0) LOADE(1) LOADE(2) LOADE(3)

  const float* emit_base = inputs + (size_t)b * Lc * NTAGS;
  const float* pe = emit_base + lr;  // row offsets lr+16k via +16k*1
  const int* mask_b = mask + b * Lc;

  int Msum = 0;
  int rep;  // lane0's stored word0 bits (v[0]), carried in register
  {
    // init at word==lane -> j = sigma^{-1}(lane) = lr + 16c
    const int j = lr + 16 * c;
    float iv;
    if (!bwd) {
      iv = (j == START_T) ? 1.0f : 0.0f;
    } else {
      const float rr = __expf(trans[STOP_T * NTAGS + j]);
      const float wl = (mask_b[Lc - 1] != 0)
                           ? __expf(emit_base[(size_t)(Lc - 1) * NTAGS + j])
                           : 1.0f;
      iv = rr * wl;
    }
    vb1[lane] = iv;
    rep = __builtin_amdgcn_readfirstlane(__float_as_int(iv));
  }
  __builtin_amdgcn_wave_barrier();

  float4 u0, u1, u2, u3;
#define ULOAD               \
  {                         \
    u0 = vb4[4 * c + 0];    \
    u1 = vb4[4 * c + 1];    \
    u2 = vb4[4 * c + 2];    \
    u3 = vb4[4 * c + 3];    \
  }
  ULOAD

#define ROWF(k)                                        \
    v2f a##k##0 = E##k##_0 * (v2f){u0.x, u0.y};        \
    v2f a##k##1 = E##k##_1 * (v2f){u0.z, u0.w};        \
    a##k##0 += E##k##_2 * (v2f){u1.x, u1.y};           \
    a##k##1 += E##k##_3 * (v2f){u1.z, u1.w};           \
    a##k##0 += E##k##_4 * (v2f){u2.x, u2.y};           \
    a##k##1 += E##k##_5 * (v2f){u2.z, u2.w};           \
    a##k##0 += E##k##_6 * (v2f){u3.x, u3.y};           \
    a##k##1 += E##k##_7 * (v2f){u3.z, u3.w};

#define STEP(W0, W1, W2, W3, MIDX)                                     \
  {                                                                    \
    const unsigned e0 = ((unsigned)rep >> 23) & 0xffu;                 \
    const int d = (e0 == 0u) ? 0 : (int)e0 - 127;                      \
    Msum += d;                                                         \
    const float rs = __uint_as_float((unsigned)(127 - d) << 23);       \
    const int mv = __builtin_amdgcn_readlane(mrow, (MIDX));            \
    float s0, s1, s2, s3;                                              \
    if (__builtin_expect(mv, 1)) {                                     \
      ROWF(0) ROWF(1) ROWF(2) ROWF(3)                                  \
      v2f t0 = a00 + a01, t1 = a10 + a11;                              \
      v2f t2 = a20 + a21, t3 = a30 + a31;                              \
      float r0 = t0.x + t0.y, r1 = t1.x + t1.y;                        \
      float r2 = t2.x + t2.y, r3 = t3.x + t3.y;                        \
      r0 = dpp_add<0xB1>(r0); r1 = dpp_add<0xB1>(r1);                  \
      r2 = dpp_add<0xB1>(r2); r3 = dpp_add<0xB1>(r3);                  \
      r0 = dpp_add<0x4E>(r0); r1 = dpp_add<0x4E>(r1);                  \
      r2 = dpp_add<0x4E>(r2); r3 = dpp_add<0x4E>(r3);                  \
      s0 = r0 * ((W0) * rs); s1 = r1 * ((W1) * rs);                    \
      s2 = r2 * ((W2) * rs); s3 = r3 * ((W3) * rs);                    \
    } else {                                                           \
      v2f q0 = ((v2f){u0.x, u0.y} + (v2f){u0.z, u0.w}) +               \
               ((v2f){u1.x, u1.y} + (v2f){u1.z, u1.w});                \
      v2f q1 = ((v2f){u2.x, u2.y} + (v2f){u2.z, u2.w}) +               \
               ((v2f){u3.x, u3.y} + (v2f){u3.z, u3.w});                \
      v2f qq = q0 + q1;                                                \
      float ss = qq.x + qq.y;                                          \
      ss = dpp_add<0xB1>(ss); ss = dpp_add<0x4E>(ss);                  \
      ss *= rs;                                                        \
      s0 = bwd ? ss * (W0) : ss; s1 = bwd ? ss * (W1) : ss;            \
      s2 = bwd ? ss * (W2) : ss; s3 = bwd ? ss * (W3) : ss;            \
    }                                                                  \
    const float slo = (c & 1) ? s1 : s0;                               \
    const float shi = (c & 1) ? s3 : s2;                               \
    const float sw = (c & 2) ? shi : slo;                              \
    rep = __builtin_amdgcn_readfirstlane(__float_as_int(sw));          \
    __builtin_amdgcn_wave_barrier();                                   \
    vb1[lane] = sw;                                                    \
    __builtin_amdgcn_wave_barrier();                                   \
    ULOAD                                                              \
  }

  // W prefetch, rows lr+16k. fwd: exp(emit[k][row]).
  // bwd step k: w'_(510-k), gated by mask; k >= HL-1 -> 1.
  float wA[4][4], wB[4][4];
#define PRE(W, ST)                                                     \
  {                                                                    \
    _Pragma("unroll") for (int q_ = 0; q_ < 4; ++q_) {                 \
      const int k_ = (ST) + q_;                                        \
      if (!bwd) {                                                      \
        const int kk = (k_ < HL) ? k_ : (HL - 1);                      \
        const float* pp = pe + (size_t)kk * NTAGS;                     \
        W[q_][0] = __expf(pp[0]);                                      \
        W[q_][1] = __expf(pp[16]);                                     \
        W[q_][2] = __expf(pp[32]);                                     \
        W[q_][3] = __expf(pp[48]);                                     \
      } else if (k_ >= HL - 1) {                                       \
        W[q_][0] = W[q_][1] = W[q_][2] = W[q_][3] = 1.0f;              \
      } else {                                                         \
        const int e_ = (Lc - 2) - k_;                                  \
        if (mask_b[e_] != 0) {                                         \
          const float* pp = pe + (size_t)e_ * NTAGS;                   \
          W[q_][0] = __expf(pp[0]);                                    \
          W[q_][1] = __expf(pp[16]);                                   \
          W[q_][2] = __expf(pp[32]);                                   \
          W[q_][3] = __expf(pp[48]);                                   \
        } else {                                                       \
          W[q_][0] = W[q_][1] = W[q_][2] = W[q_][3] = 1.0f;            \
        }                                                              \
      }                                                                \
    }                                                                  \
  }

  PRE(wA, 0)
  int mrow = mask_b[bwd ? (Lc - 1 - lane) : lane];

  for (int cc = 0; cc < 4; ++cc) {
    const int nc = (cc < 3) ? cc + 1 : cc;
    const int mrow_nxt =
        mask_b[bwd ? (Lc - 1 - nc * 64 - lane) : (nc * 64 + lane)];
    for (int gp = 0; gp < 8; ++gp) {
      const int base = cc * 64 + gp * 8;
      const int mb = gp * 8;
      PRE(wB, base + 4)
      STEP(wA[0][0], wA[0][1], wA[0][2], wA[0][3], mb + 0)
      STEP(wA[1][0], wA[1][1], wA[1][2], wA[1][3], mb + 1)
      STEP(wA[2][0], wA[2][1], wA[2][2], wA[2][3], mb + 2)
      STEP(wA[3][0], wA[3][1], wA[3][2], wA[3][3], mb + 3)
      PRE(wA, base + 8)
      STEP(wB[0][0], wB[0][1], wB[0][2], wB[0][3], mb + 4)
      STEP(wB[1][0], wB[1][1], wB[1][2], wB[1][3], mb + 5)
      STEP(wB[2][0], wB[2][1], wB[2][2], wB[2][3], mb + 6)
      STEP(wB[3][0], wB[3][1], wB[3][2], wB[3][3], mb + 7)
    }
    mrow = mrow_nxt;
  }

  // final half-state (sigma-order; both halves share sigma so dot is direct)
  hv[(size_t)bid * NTAGS + lane] = vb1[lane];
  if (lane == 0) msum_out[bid] = Msum;
}

// ---------------------------------------------------------------------------
// Numerator score (exact): one wave per batch.
// ---------------------------------------------------------------------------
__global__ void crf_num(const float* __restrict__ inputs,
                        const int* __restrict__ tags,
                        const int* __restrict__ mask,
                        const float* __restrict__ trans,
                        float* __restrict__ num) {
  const int b = blockIdx.x;
  const int lane = threadIdx.x;
  const float* emit_base = inputs + (size_t)b * Lc * NTAGS;
  const int* tags_b = tags + b * Lc;
  const int* mask_b = mask + b * Lc;

  float sc = 0.0f;
  for (int l = lane; l < Lc; l += 64) {
    int tl = tags_b[l];
    float mfl = (float)mask_b[l];
    if (l < Lc - 1) {
      int tn = tags_b[l + 1];
      float mfn = (float)mask_b[l + 1];
      sc += trans[tn * NTAGS + tl] * mfn +
            emit_base[(size_t)l * NTAGS + tl] * mfl;
    } else {
      sc += trans[STOP_T * NTAGS + tl] +
            emit_base[(size_t)l * NTAGS + tl] * mfl;
    }
  }
  if (lane == 0) sc += trans[tags_b[0] * NTAGS + START_T];
  float score = wave_sum(sc);
  if (lane == 0) num[b] = score;
}

// ---------------------------------------------------------------------------
// Join: partial[b] = num[b] - ( log(f_256 . z_256) + (MsF+MsB) ln2 )
// ---------------------------------------------------------------------------
__global__ void crf_join(const float* __restrict__ hv,
                         const int* __restrict__ msum,
                         const float* __restrict__ num,
                         float* __restrict__ partial) {
  const int b = blockIdx.x;
  const int lane = threadIdx.x;
  const float prod = hv[(size_t)b * NTAGS + lane] *
                     hv[(size_t)(b + Bc) * NTAGS + lane];
  const float sden = wave_sum(prod);
  if (lane == 0) {
    const float mf = (float)(msum[b] + msum[b + Bc]);
    const float C = fmaf(mf, -2.1219444e-4f, mf * 0.693359375f);
    partial[b] = num[b] - (__logf(sden) + C);
  }
}

__global__ void crf_reduce(const float* __restrict__ partial,
                           float* __restrict__ out) {
  const int lane = threadIdx.x;
  float s = 0.0f;
  for (int i = lane; i < Bc; i += 64) s += partial[i];
  s = wave_sum(s);
  if (lane == 0) out[0] = s;
}

}  // namespace

extern "C" void kernel_launch(void* const* d_in, const int* in_sizes, int n_in,
                              void* d_out, int out_size, void* d_ws,
                              size_t ws_size, hipStream_t stream) {
  const float* inputs = (const float*)d_in[0];
  const int* tags = (const int*)d_in[1];
  const int* mask = (const int*)d_in[2];
  const float* trans = (const float*)d_in[3];
  float* out = (float*)d_out;

  float* num = (float*)d_ws;               // [512]
  float* partial = num + Bc;               // [512]
  float* hv = partial + Bc;                // [1024][64]
  int* msum = (int*)(hv + 2 * Bc * NTAGS); // [1024]

  crf_scan<<<2 * Bc, 64, 0, stream>>>(inputs, mask, trans, hv, msum);
  crf_num<<<Bc, 64, 0, stream>>>(inputs, tags, mask, trans, num);
  crf_join<<<Bc, 64, 0, stream>>>(hv, msum, num, partial);
  crf_reduce<<<1, 64, 0, stream>>>(partial, out);
}